// Round 17
// baseline (33.569 us; speedup 1.0000x reference)
//
#include <hip/hip_runtime.h>

#define T_LEN 768
#define TC 32                 // timesteps per chunk
#define NCH (T_LEN / TC)      // 24 chunks
#define RPB 16                // rows per block (consumer: cols 0..31 meaningful)
#define RS  66                // r1buf stride: [t][lane]
#define OS  66                // lds_o stride: [t][lane]

struct Params { const float* p[27]; };

__device__ __forceinline__ float ex2(float x){ float r; asm("v_exp_f32 %0, %1":"=v"(r):"v"(x)); return r; }
__device__ __forceinline__ float frcp(float x){ return __builtin_amdgcn_rcpf(x); }
__device__ __forceinline__ float dpp_xor1(float x){
    // lane <-> lane^1 swap, quad_perm [1,0,3,2]; pure VALU
    return __int_as_float(__builtin_amdgcn_mov_dpp(__float_as_int(x),0xB1,0xF,0xF,true));
}
__device__ __forceinline__ float psig(float v, float k, float c){
    return frcp(1.0f + ex2(__builtin_fmaf(-k, v, c)));
}

// TLP experiment: 1024 blocks x 128 threads (4 blocks/CU -> 4 consumer waves
// per CU, ~1 per SIMD, so two+ independent serial chains interleave per SIMD
// pair and fill each other's latency stalls).
// wave0 = consumer: R16's trans-free chain, 16 rows in cols 0..31; lanes
// 32-63 run identical code on unused LDS cols (no divergence, garbage never
// drained, dpp pairs stay within halves).
// wave1 = producer: loads (2-chunk-ahead regs) + input sigmoids + drains.
__global__ __launch_bounds__(128, 2) void cell_kernel(Params P, float* __restrict__ out) {
    __shared__ float r1buf[2][TC][RS];    // [buf][t][chan-col] input sigmas
    __shared__ float lds_o[2][TC][OS];    // [buf][t][chan-col] output proxy

    const int tid = (int)threadIdx.x;
    const int r0  = (int)blockIdx.x * RPB;
    const int wv  = tid >> 6;             // 0 = consumer, 1 = producer
    const int l   = tid & 63;

    const float* __restrict__ inp = P.p[0];
    const float capx = P.p[1][0], capy = P.p[2][0];
    const float g_ax = P.p[3][0],  m_ax = P.p[4][0],  s_ax = P.p[5][0],  q_ax = P.p[6][0];
    const float g_by = P.p[7][0],  m_by = P.p[8][0],  s_by = P.p[9][0],  q_by = P.p[10][0];
    const float g_xx = P.p[11][0], m_xx = P.p[12][0], s_xx = P.p[13][0], q_xx = P.p[14][0];
    const float g_xy = P.p[15][0], m_xy = P.p[16][0], s_xy = P.p[17][0], q_xy = P.p[18][0];
    const float g_yx = P.p[19][0], m_yx = P.p[20][0], s_yx = P.p[21][0], q_yx = P.p[22][0];
    const float g_yy = P.p[23][0], m_yy = P.p[24][0], s_yy = P.p[25][0], q_yy = P.p[26][0];

    const float icx = 1.0f / capx, icy = 1.0f / capy;
    const float L2E  = 1.44269504088896340736f;
    const float mLN2 = -0.69314718056f;

    // input-synapse sigmoids (producer)
    const float k1x = s_ax * L2E, c1x = k1x * m_ax;
    const float k1y = s_by * L2E, c1y = k1y * m_by;

    const bool share = (s_yx == s_yy) && (m_yx == m_yy) &&
                       (s_xy == s_xx) && (m_xy == m_xx) &&
                       (s_xx != 0.0f) && (s_yy != 0.0f) &&
                       (g_xx != 0.0f) && (g_yy != 0.0f);

    // drain map (producer): v_x = fma(stored, cv1, cv0)
    const float k2xp = s_xx * L2E, c2xp = k2xp * m_xx;
    const float G2xp = g_xx * icx;
    const float A2xp = g_xx * q_xx * icx;
    const float R2xp = __builtin_fmaf(G2xp, c2xp, -k2xp * A2xp);
    const float cv1 = share ? 1.0f / (G2xp * k2xp) : 1.0f;
    const float cv0 = share ? (c2xp / k2xp - R2xp * (1.0f / (G2xp * k2xp))) : 0.0f;

    const float4* __restrict__ in4 = (const float4*)inp;     // row stride 384 f4

    if (wv != 0) {
        // ================= PRODUCER (wave 1) =================
        float4 pinA[4], pinB[4];                             // 2-chunk-ahead regs

        auto LOADP = [&](float4 (&pin)[4], int c) {          // 16 rows x 16 f4
            #pragma unroll
            for (int k = 0; k < 4; ++k) { int idx = l + 64*k;
                int r_ = idx >> 4, q = idx & 15;
                pin[k] = in4[(size_t)(r0 + r_) * 384 + c * 16 + q]; }
        };
        auto SIGW = [&](float4 (&pin)[4], int buf) {
            #pragma unroll
            for (int k = 0; k < 4; ++k) { int idx = l + 64*k;
                int r_ = idx >> 4, q = idx & 15;             // chan-cols 2r_, 2r_+1
                float2 w0, w1;                               // [t][chan] layout
                w0.x = psig(pin[k].x, k1x, c1x);             // a_{2q}  -> col 2r_
                w0.y = psig(pin[k].y, k1y, c1y);             // b_{2q}  -> col 2r_+1
                w1.x = psig(pin[k].z, k1x, c1x);             // a_{2q+1}
                w1.y = psig(pin[k].w, k1y, c1y);             // b_{2q+1}
                *(float2*)&r1buf[buf][2*q]    [2*r_] = w0;
                *(float2*)&r1buf[buf][2*q + 1][2*r_] = w1; }
        };
        auto DRAIN = [&](int c) {       // chunk c (buf c&1), h2 -> v map
            const int buf = c & 1;
            #pragma unroll
            for (int k = 0; k < 2; ++k) { int f = l + 64*k;
                int r_ = f >> 3, pq = f & 7;                 // 16 rows x 8 f4
                float4 o;
                o.x = __builtin_fmaf(lds_o[buf][4*pq + 0][2*r_], cv1, cv0);
                o.y = __builtin_fmaf(lds_o[buf][4*pq + 1][2*r_], cv1, cv0);
                o.z = __builtin_fmaf(lds_o[buf][4*pq + 2][2*r_], cv1, cv0);
                o.w = __builtin_fmaf(lds_o[buf][4*pq + 3][2*r_], cv1, cv0);
                *(float4*)&out[(size_t)(r0 + r_) * T_LEN + c * TC + 4*pq] = o; }
        };

        LOADP(pinA, 0);
        LOADP(pinB, 1);
        SIGW(pinA, 0);                   // chunk 0 sigmas ready
        __syncthreads();
        for (int c = 0; c < NCH; ++c) {
            if (c + 2 < NCH) { if ((c & 1) == 0) LOADP(pinA, c + 2);
                               else              LOADP(pinB, c + 2); }
            if (c >= 1) DRAIN(c - 1);    // drain under load latency
            if (c + 1 < NCH) {           // sigmas for chunk c+1 (loaded @ c-1)
                if ((c & 1) == 0) SIGW(pinB, (c + 1) & 1);
                else              SIGW(pinA, (c + 1) & 1);
            }
            __syncthreads();
        }
        DRAIN(NCH - 1);
    } else {
        // ================= CONSUMER (wave 0) — R16's proven chain =================
        __builtin_amdgcn_s_setprio(1);   // favor the serial wave on its SIMD

        const bool isX = (l & 1) == 0;
        const float k2r = (isX ? s_xx : s_yy) * L2E;
        const float c2r = k2r * (isX ? m_xx : m_yy);
        const float k3r = (isX ? s_xy : s_yx) * L2E;         // cross-OUT (general)
        const float c3r = k3r * (isX ? m_xy : m_yx);
        const float icr = isX ? icx : icy;
        const float A1r = (isX ? g_ax * q_ax : g_by * q_by) * icr, G1r = (isX ? g_ax : g_by) * icr;
        const float A2r = (isX ? g_xx * q_xx : g_yy * q_yy) * icr, G2r = (isX ? g_xx : g_yy) * icr;
        const float A3r = (isX ? g_yx * q_yx : g_xy * q_xy) * icr, G3r = (isX ? g_yx : g_xy) * icr;

        const float R1 = __builtin_fmaf(G1r, c2r, -k2r * A1r);
        const float R2 = __builtin_fmaf(G2r, c2r, -k2r * A2r);
        const float R3 = __builtin_fmaf(G3r, c2r, -k2r * A3r);
        const float mG1 = -G1r, mG2 = -G2r, mG3 = -G3r;
        const float inv_mG2 = 1.0f / mG2;

        float h1 = __builtin_fmaf(mG1, c2r, R1);
        float h2 = __builtin_fmaf(mG2, c2r, R2);
        float h3 = __builtin_fmaf(mG3, c2r, R3);
        float v = 0.0f;                  // general path

        __syncthreads();
        for (int c = 0; c < NCH; ++c) {
            const int buf = c & 1;
            float rr[TC];                // b32 reads; upper lanes read unused cols
            #pragma unroll
            for (int t = 0; t < TC; ++t) rr[t] = r1buf[buf][t][l];

            if (share) {
                float Wr  = (h2 - R2) * inv_mG2;             // exact anchor
                float E   = ex2(Wr);
                float sg  = frcp(1.0f + E);
                float t1  = __builtin_fmaf(-sg, sg, sg);
                float cfac = mLN2 * t1;
                float p1 = rr[0] * h1;
                #pragma unroll
                for (int t = 0; t < TC; ++t) {
                    float rp   = dpp_xor1(sg);               // partner sigma
                    float s2mW = __builtin_fmaf(sg, h2, p1);
                    float dl   = __builtin_fmaf(rp, h3, s2mW);
                    float sgn  = __builtin_fmaf(cfac, dl, sg);   // 1st-order step
                    h1 = __builtin_fmaf(mG1, dl, h1);
                    h2 = __builtin_fmaf(mG2, dl, h2);
                    h3 = __builtin_fmaf(mG3, dl, h3);
                    if (t + 1 < TC) p1 = rr[t + 1] * h1;
                    t1   = __builtin_fmaf(-sgn, sgn, sgn);
                    cfac = mLN2 * t1;                        // fresh slope each step
                    lds_o[buf][t][l] = h2;                   // v proxy (affine)
                    sg = sgn;
                }
            } else {
                #pragma unroll
                for (int t = 0; t < TC; ++t) {
                    float s2 = psig(v, k2r, c2r);
                    float s3 = psig(v, k3r, c3r);
                    float rp = dpp_xor1(s3);
                    float u1 = __builtin_fmaf(-v, G1r, A1r);
                    float u2 = __builtin_fmaf(-v, G2r, A2r);
                    float u3 = __builtin_fmaf(-v, G3r, A3r);
                    v = __builtin_fmaf(rp, u3,
                        __builtin_fmaf(s2, u2,
                        __builtin_fmaf(rr[t], u1, v)));
                    lds_o[buf][t][l] = v;                    // cv=(1,0)
                }
            }
            __syncthreads();
        }
    }
}

extern "C" void kernel_launch(void* const* d_in, const int* in_sizes, int n_in,
                              void* d_out, int out_size, void* d_ws, size_t ws_size,
                              hipStream_t stream) {
    (void)d_ws; (void)ws_size; (void)out_size; (void)n_in;
    Params P;
    for (int i = 0; i < 27; ++i) P.p[i] = (const float*)d_in[i];
    float* out = (float*)d_out;
    const int B = in_sizes[0] / (T_LEN * 2);   // 16384
    dim3 grid(B / RPB);                        // 1024 blocks x 128 threads (2 waves)
    cell_kernel<<<grid, dim3(128), 0, stream>>>(P, out);
}

// Round 18
// 32.849 us; speedup vs baseline: 1.0219x; 1.0219x over previous
//
#include <hip/hip_runtime.h>

#define T_LEN 768
#define TC 32                 // timesteps per chunk
#define NCH (T_LEN / TC)      // 24 chunks
#define RPB 32                // rows per block
#define RS  66                // r1buf stride: [t][lane], bank-spread reads
#define OS  66                // lds_o stride: [t][lane], conflict-free writes

struct Params { const float* p[27]; };

__device__ __forceinline__ float ex2(float x){ float r; asm("v_exp_f32 %0, %1":"=v"(r):"v"(x)); return r; }
__device__ __forceinline__ float frcp(float x){ return __builtin_amdgcn_rcpf(x); }
__device__ __forceinline__ float dpp_xor1(float x){
    // lane <-> lane^1 swap, quad_perm [1,0,3,2]; pure VALU
    return __int_as_float(__builtin_amdgcn_mov_dpp(__float_as_int(x),0xB1,0xF,0xF,true));
}
__device__ __forceinline__ float psig(float v, float k, float c){
    return frcp(1.0f + ex2(__builtin_fmaf(-k, v, c)));
}

// R16 champion (33.4us) with the last serial-loop trims:
//   - cfac (sigma slope) refreshed every 4 steps instead of every step
//   - exact exp2/rcp anchor every 2 chunks (64-step window) instead of every
// Error budget: slope staleness ~1e-5 sigma/step, 1st-order truncation over
// 64 steps ~1.7e-4 sigma -> ~4e-5 in v; all reset by the anchor.
//
// Block = 192: wave0 = serial consumer (2 lanes/row x 32 rows, ~9.5 inst/step
// chain sg -> dpp -> dl -> sg'), waves 1-2 = producers (half of loads + input
// sigmoids + drains each), loads pipelined 2 chunks ahead in registers.
__global__ __launch_bounds__(192, 1) void cell_kernel(Params P, float* __restrict__ out) {
    __shared__ float r1buf[2][TC][RS];    // [buf][t][consumer-lane] input sigmas
    __shared__ float lds_o[2][TC][OS];    // [buf][t][consumer-lane] output proxy

    const int tid = (int)threadIdx.x;
    const int r0  = (int)blockIdx.x * RPB;
    const int wv  = tid >> 6;             // 0 = consumer, 1..2 = producers
    const int l   = tid & 63;

    const float* __restrict__ inp = P.p[0];
    const float capx = P.p[1][0], capy = P.p[2][0];
    const float g_ax = P.p[3][0],  m_ax = P.p[4][0],  s_ax = P.p[5][0],  q_ax = P.p[6][0];
    const float g_by = P.p[7][0],  m_by = P.p[8][0],  s_by = P.p[9][0],  q_by = P.p[10][0];
    const float g_xx = P.p[11][0], m_xx = P.p[12][0], s_xx = P.p[13][0], q_xx = P.p[14][0];
    const float g_xy = P.p[15][0], m_xy = P.p[16][0], s_xy = P.p[17][0], q_xy = P.p[18][0];
    const float g_yx = P.p[19][0], m_yx = P.p[20][0], s_yx = P.p[21][0], q_yx = P.p[22][0];
    const float g_yy = P.p[23][0], m_yy = P.p[24][0], s_yy = P.p[25][0], q_yy = P.p[26][0];

    const float icx = 1.0f / capx, icy = 1.0f / capy;
    const float L2E  = 1.44269504088896340736f;
    const float mLN2 = -0.69314718056f;

    // input-synapse sigmoids (producers)
    const float k1x = s_ax * L2E, c1x = k1x * m_ax;
    const float k1y = s_by * L2E, c1y = k1y * m_by;

    const bool share = (s_yx == s_yy) && (m_yx == m_yy) &&
                       (s_xy == s_xx) && (m_xy == m_xx) &&
                       (s_xx != 0.0f) && (s_yy != 0.0f) &&
                       (g_xx != 0.0f) && (g_yy != 0.0f);

    // drain map (producers): v_x = fma(stored, cv1, cv0)
    const float k2xp = s_xx * L2E, c2xp = k2xp * m_xx;
    const float G2xp = g_xx * icx;
    const float A2xp = g_xx * q_xx * icx;
    const float R2xp = __builtin_fmaf(G2xp, c2xp, -k2xp * A2xp);
    const float cv1 = share ? 1.0f / (G2xp * k2xp) : 1.0f;
    const float cv0 = share ? (c2xp / k2xp - R2xp * (1.0f / (G2xp * k2xp))) : 0.0f;

    const float4* __restrict__ in4 = (const float4*)inp;     // row stride 384 f4

    if (wv != 0) {
        // ================= PRODUCERS (waves 1-2) =================
        const int p = wv - 1;                                // 0 or 1
        float4 pinA[4], pinB[4];

        auto LOADP = [&](float4 (&pin)[4], int c) {
            #pragma unroll
            for (int k = 0; k < 4; ++k) { int idx = l + 64*(p*4 + k);
                int r_ = idx >> 4, q = idx & 15;
                pin[k] = in4[(size_t)(r0 + r_) * 384 + c * 16 + q]; }
        };
        auto SIGW = [&](float4 (&pin)[4], int buf) {
            #pragma unroll
            for (int k = 0; k < 4; ++k) { int idx = l + 64*(p*4 + k);
                int r_ = idx >> 4, q = idx & 15;
                float2 w0, w1;                               // [t][lane] layout
                w0.x = psig(pin[k].x, k1x, c1x);             // a_{2q}  -> lane 2r
                w0.y = psig(pin[k].y, k1y, c1y);             // b_{2q}  -> lane 2r+1
                w1.x = psig(pin[k].z, k1x, c1x);             // a_{2q+1}
                w1.y = psig(pin[k].w, k1y, c1y);             // b_{2q+1}
                *(float2*)&r1buf[buf][2*q]    [2*r_] = w0;   // b64, <=4-way
                *(float2*)&r1buf[buf][2*q + 1][2*r_] = w1; }
        };
        auto DRAIN = [&](int c) {       // chunk c (buf c&1), h2 -> v map
            const int buf = c & 1;
            #pragma unroll
            for (int k = 0; k < 2; ++k) { int f = l + 64*(p*2 + k);
                int r_ = f >> 3, pq = f & 7;
                float4 o;
                o.x = __builtin_fmaf(lds_o[buf][4*pq + 0][2*r_], cv1, cv0);
                o.y = __builtin_fmaf(lds_o[buf][4*pq + 1][2*r_], cv1, cv0);
                o.z = __builtin_fmaf(lds_o[buf][4*pq + 2][2*r_], cv1, cv0);
                o.w = __builtin_fmaf(lds_o[buf][4*pq + 3][2*r_], cv1, cv0);
                *(float4*)&out[(size_t)(r0 + r_) * T_LEN + c * TC + 4*pq] = o; }
        };

        LOADP(pinA, 0);
        LOADP(pinB, 1);
        SIGW(pinA, 0);                   // chunk 0 sigmas ready
        __syncthreads();
        for (int c = 0; c < NCH; ++c) {
            // refill the slot freed by last iteration's SIGW (chunk c+2)
            if (c + 2 < NCH) { if ((c & 1) == 0) LOADP(pinA, c + 2);
                               else              LOADP(pinB, c + 2); }
            if (c >= 1) DRAIN(c - 1);    // drain under load latency
            if (c + 1 < NCH) {           // sigmas for chunk c+1 (loaded @ c-1)
                if ((c & 1) == 0) SIGW(pinB, (c + 1) & 1);
                else              SIGW(pinA, (c + 1) & 1);
            }
            __syncthreads();
        }
        DRAIN(NCH - 1);
    } else {
        // ================= CONSUMER (wave 0) — trimmed chain =================
        __builtin_amdgcn_s_setprio(1);   // favor the serial wave on its SIMD

        const bool isX = (l & 1) == 0;
        const float k2r = (isX ? s_xx : s_yy) * L2E;
        const float c2r = k2r * (isX ? m_xx : m_yy);
        const float k3r = (isX ? s_xy : s_yx) * L2E;         // cross-OUT (general)
        const float c3r = k3r * (isX ? m_xy : m_yx);
        const float icr = isX ? icx : icy;
        const float A1r = (isX ? g_ax * q_ax : g_by * q_by) * icr, G1r = (isX ? g_ax : g_by) * icr;
        const float A2r = (isX ? g_xx * q_xx : g_yy * q_yy) * icr, G2r = (isX ? g_xx : g_yy) * icr;
        const float A3r = (isX ? g_yx * q_yx : g_xy * q_xy) * icr, G3r = (isX ? g_yx : g_xy) * icr;

        const float R1 = __builtin_fmaf(G1r, c2r, -k2r * A1r);
        const float R2 = __builtin_fmaf(G2r, c2r, -k2r * A2r);
        const float R3 = __builtin_fmaf(G3r, c2r, -k2r * A3r);
        const float mG1 = -G1r, mG2 = -G2r, mG3 = -G3r;
        const float inv_mG2 = 1.0f / mG2;

        float h1 = __builtin_fmaf(mG1, c2r, R1);
        float h2 = __builtin_fmaf(mG2, c2r, R2);
        float h3 = __builtin_fmaf(mG3, c2r, R3);
        float v = 0.0f;                  // general path
        float sg = 0.0f, cfac = 0.0f;    // carried across chunks (share path)

        __syncthreads();
        for (int c = 0; c < NCH; ++c) {
            const int buf = c & 1;
            float rr[TC];                // conflict-free b32 reads ([t][l])
            #pragma unroll
            for (int t = 0; t < TC; ++t) rr[t] = r1buf[buf][t][l];

            if (share) {
                if ((c & 1) == 0) {                          // anchor every 2 chunks
                    float Wr = (h2 - R2) * inv_mG2;          // W from h2 (exact affine)
                    float E  = ex2(Wr);
                    sg = frcp(1.0f + E);
                    float t1 = __builtin_fmaf(-sg, sg, sg);
                    cfac = mLN2 * t1;                        // -ln2*sg*(1-sg)
                }
                float p1 = rr[0] * h1;
                #pragma unroll
                for (int t = 0; t < TC; ++t) {
                    float rp   = dpp_xor1(sg);               // partner sigma
                    float s2mW = __builtin_fmaf(sg, h2, p1);
                    float dl   = __builtin_fmaf(rp, h3, s2mW);
                    float sgn  = __builtin_fmaf(cfac, dl, sg);   // 1st-order step
                    h1 = __builtin_fmaf(mG1, dl, h1);
                    h2 = __builtin_fmaf(mG2, dl, h2);
                    h3 = __builtin_fmaf(mG3, dl, h3);
                    if (t + 1 < TC) p1 = rr[t + 1] * h1;
                    if ((t & 3) == 3) {                      // slope refresh /4 steps
                        float t1 = __builtin_fmaf(-sgn, sgn, sgn);
                        cfac = mLN2 * t1;
                    }
                    lds_o[buf][t][l] = h2;                   // v proxy (affine)
                    sg = sgn;
                }
            } else {
                #pragma unroll
                for (int t = 0; t < TC; ++t) {
                    float s2 = psig(v, k2r, c2r);
                    float s3 = psig(v, k3r, c3r);
                    float rp = dpp_xor1(s3);
                    float u1 = __builtin_fmaf(-v, G1r, A1r);
                    float u2 = __builtin_fmaf(-v, G2r, A2r);
                    float u3 = __builtin_fmaf(-v, G3r, A3r);
                    v = __builtin_fmaf(rp, u3,
                        __builtin_fmaf(s2, u2,
                        __builtin_fmaf(rr[t], u1, v)));
                    lds_o[buf][t][l] = v;                    // cv=(1,0)
                }
            }
            __syncthreads();
        }
    }
}

extern "C" void kernel_launch(void* const* d_in, const int* in_sizes, int n_in,
                              void* d_out, int out_size, void* d_ws, size_t ws_size,
                              hipStream_t stream) {
    (void)d_ws; (void)ws_size; (void)out_size; (void)n_in;
    Params P;
    for (int i = 0; i < 27; ++i) P.p[i] = (const float*)d_in[i];
    float* out = (float*)d_out;
    const int B = in_sizes[0] / (T_LEN * 2);   // 16384
    dim3 grid(B / RPB);                        // 512 blocks x 192 threads (3 waves)
    cell_kernel<<<grid, dim3(192), 0, stream>>>(P, out);
}